// Round 2
// baseline (400.195 us; speedup 1.0000x reference)
//
#include <hip/hip_runtime.h>
#include <math.h>

#define NB  32
#define TDS 2048
#define LL  512
#define DD  256
#define DC  64   // D/RATIO
#define GAP_THR 1e-3f

// ---------------------------------------------------------------------------
// ws layout (floats):
//   [0, NB*LL*DD)        : KP   = k + pe_k        (16.78 MB)
//   then TDS*DD          : PEQ  = pe_q (w_s = 1)  (2 MB)
//   then NB*TDS ints     : IDX  = argmax indices
//   then 1 int           : CNT  = flagged-row counter
//   then NB*TDS ints     : FLAGS= flagged (b<<11|t) rows
// ---------------------------------------------------------------------------

__global__ void init_cnt_kernel(int* __restrict__ cnt) {
    if (threadIdx.x == 0) cnt[0] = 0;
}

__global__ void peq_kernel(float* __restrict__ peq) {
    int idx = blockIdx.x * 256 + threadIdx.x;        // < TDS*DD
    int t = idx >> 8;
    int d = idx & 255;
    int i = d >> 1;
    // invdiv = 10000^(-i/128) via f64 exp (|rel err| ~1e-15, irrelevant)
    double invdiv = exp((double)i * (-9.210340371976184 / 128.0));
    double ang = (double)t * invdiv;                 // f64 angle
    double s, c;
    sincos(ang, &s, &c);
    peq[idx] = (float)((d & 1) ? c : s);
}

__global__ void kp_kernel(const float* __restrict__ k,
                          const int* __restrict__ text_lengths,
                          const int* __restrict__ mel_lengths,
                          float* __restrict__ kp) {
    int idx = blockIdx.x * 256 + threadIdx.x;        // < NB*LL*DD
    int b = idx >> 17;                                // / (LL*DD)
    int r = idx & ((LL * DD) - 1);
    int l = r >> 8;
    int d = r & 255;
    int i = d >> 1;
    double ws = ((double)mel_lengths[b] * 0.25) / (double)text_lengths[b];
    double invdiv = exp((double)i * (-9.210340371976184 / 128.0));
    double ang = ws * (double)l * invdiv;            // f64 angle
    double s, c;
    sincos(ang, &s, &c);
    kp[idx] = k[idx] + (float)((d & 1) ? c : s);
}

// ---------------------------------------------------------------------------
// score kernel: per block 64 rows (t) x 512 cols (l): scores, masked softmax,
// align write, top-2 argmax -> IDX, near-ties flagged for f64 refinement.
// 512 threads = 8 waves; wave owns 8 rows; lane owns cols {4c..4c+3, 256+4c..}
// ---------------------------------------------------------------------------
__global__ __launch_bounds__(512, 2)
void score_kernel(const float* __restrict__ q,
                  const float* __restrict__ kp,
                  const float* __restrict__ peq,
                  const int* __restrict__ text_lengths,
                  const int* __restrict__ mel_lengths,
                  float* __restrict__ align_out,
                  int* __restrict__ idx_out,
                  int* __restrict__ flag_cnt,
                  int* __restrict__ flags) {
    __shared__ float As[16 * 68];     // [kk][t], pad 68
    __shared__ float Bs[16 * 516];    // [kk][l], pad 516
    const int b    = blockIdx.y;
    const int t0   = blockIdx.x * 64;
    const int tid  = threadIdx.x;
    const int wave = tid >> 6;
    const int lane = tid & 63;
    const int tlen = text_lengths[b];
    const int melq = mel_lengths[b] >> 2;

    const float* qb   = q   + ((size_t)b * TDS + t0) * DD;
    const float* kpb  = kp  + (size_t)b * LL * DD;
    const float* peqb = peq + (size_t)t0 * DD;

    float acc[8][8];
#pragma unroll
    for (int i = 0; i < 8; ++i)
#pragma unroll
        for (int j = 0; j < 8; ++j) acc[i][j] = 0.f;

    const int ta = tid >> 3;          // 0..63 (A row)
    const int ka = (tid & 7) * 2;     // even kk
    const int lb = tid >> 2;          // 0..127 (B row, + p*128)
    const int ub = tid & 3;           // d-chunk

    for (int ks = 0; ks < 16; ++ks) {
        const int d0 = ks * 16;
        __syncthreads();
        // stage A: qp = (q + peq) * D^-0.5
        float2 qv = *(const float2*)(qb + (size_t)ta * DD + d0 + ka);
        float2 pv = *(const float2*)(peqb + (size_t)ta * DD + d0 + ka);
        As[(ka + 0) * 68 + ta] = (qv.x + pv.x) * 0.0625f;
        As[(ka + 1) * 68 + ta] = (qv.y + pv.y) * 0.0625f;
        // stage B (transpose to [kk][l])
#pragma unroll
        for (int p = 0; p < 4; ++p) {
            int l = lb + p * 128;
            float4 kv = *(const float4*)(kpb + (size_t)l * DD + d0 + ub * 4);
            Bs[(ub * 4 + 0) * 516 + l] = kv.x;
            Bs[(ub * 4 + 1) * 516 + l] = kv.y;
            Bs[(ub * 4 + 2) * 516 + l] = kv.z;
            Bs[(ub * 4 + 3) * 516 + l] = kv.w;
        }
        __syncthreads();
#pragma unroll
        for (int kk = 0; kk < 16; ++kk) {
            float4 a0 = *(const float4*)(As + kk * 68 + wave * 8);
            float4 a1 = *(const float4*)(As + kk * 68 + wave * 8 + 4);
            float4 b0 = *(const float4*)(Bs + kk * 516 + lane * 4);
            float4 b1 = *(const float4*)(Bs + kk * 516 + 256 + lane * 4);
            const float av[8] = {a0.x, a0.y, a0.z, a0.w, a1.x, a1.y, a1.z, a1.w};
            const float bv[8] = {b0.x, b0.y, b0.z, b0.w, b1.x, b1.y, b1.z, b1.w};
#pragma unroll
            for (int i = 0; i < 8; ++i)
#pragma unroll
                for (int j = 0; j < 8; ++j)
                    acc[i][j] = fmaf(av[i], bv[j], acc[i][j]);
        }
    }

    const float NEGINF = -__builtin_inff();
    // text mask
#pragma unroll
    for (int i = 0; i < 8; ++i) {
#pragma unroll
        for (int j = 0; j < 8; ++j) {
            int l = (j < 4) ? (lane * 4 + j) : (256 + lane * 4 + (j - 4));
            if (l >= tlen) acc[i][j] = NEGINF;
        }
    }
    // per-row top-2 (value,index) on raw scores; b1v doubles as softmax max
    float b1v[8]; int b1i[8]; float b2v[8];
#pragma unroll
    for (int i = 0; i < 8; ++i) {
        float v1 = acc[i][0]; int i1 = lane * 4; float v2 = NEGINF;
#pragma unroll
        for (int j = 1; j < 8; ++j) {
            int l = (j < 4) ? (lane * 4 + j) : (256 + lane * 4 + (j - 4));
            float v = acc[i][j];
            if (v > v1)      { v2 = v1; v1 = v; i1 = l; }
            else if (v > v2) { v2 = v; }
        }
        b1v[i] = v1; b1i[i] = i1; b2v[i] = v2;
    }
#pragma unroll
    for (int off = 1; off <= 32; off <<= 1) {
#pragma unroll
        for (int i = 0; i < 8; ++i) {
            float ov = __shfl_xor(b1v[i], off, 64);
            int   oi = __shfl_xor(b1i[i], off, 64);
            float o2 = __shfl_xor(b2v[i], off, 64);
            if (ov > b1v[i]) {
                b2v[i] = fmaxf(b1v[i], o2);
                b1v[i] = ov; b1i[i] = oi;
            } else if (ov < b1v[i]) {
                b2v[i] = fmaxf(b2v[i], ov);
            } else { // equal maxima in different cols -> gap 0, keep min index
                b1i[i] = min(b1i[i], oi);
                b2v[i] = b1v[i];
            }
        }
    }
    // p = exp(s - m) (in place), row sums
    float s[8];
#pragma unroll
    for (int i = 0; i < 8; ++i) {
        float ss = 0.f;
#pragma unroll
        for (int j = 0; j < 8; ++j) {
            float pvv = expf(acc[i][j] - b1v[i]);
            acc[i][j] = pvv;
            ss += pvv;
        }
        s[i] = ss;
    }
#pragma unroll
    for (int off = 32; off >= 1; off >>= 1)
#pragma unroll
        for (int i = 0; i < 8; ++i) s[i] += __shfl_xor(s[i], off, 64);
    // write align + idx (+ flag near-ties for f64 refinement)
#pragma unroll
    for (int i = 0; i < 8; ++i) {
        int t = t0 + wave * 8 + i;
        bool mmask = (t >= melq);
        float inv = 1.0f / s[i];
        float4 o0, o1;
        o0.x = mmask ? 0.f : acc[i][0] * inv;
        o0.y = mmask ? 0.f : acc[i][1] * inv;
        o0.z = mmask ? 0.f : acc[i][2] * inv;
        o0.w = mmask ? 0.f : acc[i][3] * inv;
        o1.x = mmask ? 0.f : acc[i][4] * inv;
        o1.y = mmask ? 0.f : acc[i][5] * inv;
        o1.z = mmask ? 0.f : acc[i][6] * inv;
        o1.w = mmask ? 0.f : acc[i][7] * inv;
        size_t base = ((size_t)(b * TDS + t)) * LL;
        *(float4*)(align_out + base + lane * 4)       = o0;
        *(float4*)(align_out + base + 256 + lane * 4) = o1;
        if (lane == i) {
            idx_out[b * TDS + t] = b1i[i];
            if (!mmask && (b1v[i] - b2v[i]) < GAP_THR) {
                int pos = atomicAdd(flag_cnt, 1);
                flags[pos] = (b << 11) | t;
            }
        }
    }
}

// ---------------------------------------------------------------------------
// refine kernel: recompute flagged rows' 512 scores fully in f64, fix idx.
// ---------------------------------------------------------------------------
__global__ __launch_bounds__(256)
void refine_kernel(const float* __restrict__ q,
                   const float* __restrict__ k,
                   const int* __restrict__ text_lengths,
                   const int* __restrict__ mel_lengths,
                   const int* __restrict__ flags,
                   const int* __restrict__ flag_cnt,
                   int* __restrict__ idx_out) {
    __shared__ double qd[DD];
    __shared__ double invdiv[128];
    __shared__ double rbest[4];
    __shared__ int    ribest[4];
    const int tid = threadIdx.x;
    if (tid < 128)
        invdiv[tid] = 1.0 / pow(10000.0, (double)tid * (1.0 / 128.0));
    const int cnt = flag_cnt[0];
    for (int r = blockIdx.x; r < cnt; r += gridDim.x) {
        const int code = flags[r];
        const int b = code >> 11, t = code & 2047;
        const int tlen = text_lengths[b];
        const double ws = ((double)mel_lengths[b] * 0.25) / (double)text_lengths[b];
        __syncthreads();   // protect qd/invdiv/rbest reuse across iterations
        {
            const int d = tid, i = d >> 1;
            double ang = (double)t * invdiv[i];
            double sn, cs;
            sincos(ang, &sn, &cs);
            qd[d] = ((double)q[((size_t)b * TDS + t) * DD + d] + ((d & 1) ? cs : sn)) * 0.0625;
        }
        __syncthreads();
        double best = -1.0e300; int bi = 0x7fffffff;
        for (int p = 0; p < 2; ++p) {
            const int l = tid + p * 256;
            if (l < tlen) {
                const float* kr = k + ((size_t)b * LL + l) * DD;
                const double wl = ws * (double)l;
                double sacc = 0.0;
                for (int i = 0; i < 128; ++i) {
                    double ang = wl * invdiv[i];
                    double sn, cs;
                    sincos(ang, &sn, &cs);
                    sacc += ((double)kr[2 * i]     + sn) * qd[2 * i];
                    sacc += ((double)kr[2 * i + 1] + cs) * qd[2 * i + 1];
                }
                if (sacc > best || (sacc == best && l < bi)) { best = sacc; bi = l; }
            }
        }
        for (int off = 1; off <= 32; off <<= 1) {
            double ov = __shfl_xor(best, off, 64);
            int   oi = __shfl_xor(bi, off, 64);
            if (ov > best || (ov == best && oi < bi)) { best = ov; bi = oi; }
        }
        const int wv = tid >> 6;
        if ((tid & 63) == 0) { rbest[wv] = best; ribest[wv] = bi; }
        __syncthreads();
        if (tid == 0) {
            double bb = rbest[0]; int ii = ribest[0];
            for (int w = 1; w < 4; ++w)
                if (rbest[w] > bb || (rbest[w] == bb && ribest[w] < ii)) { bb = rbest[w]; ii = ribest[w]; }
            idx_out[b * TDS + t] = ii;
        }
    }
}

// ---------------------------------------------------------------------------
// compress kernel: out[b,c,t] = sum_d w[c,d] * v[b, idx[b,t], d] (0 if masked)
// ---------------------------------------------------------------------------
__global__ __launch_bounds__(256, 4)
void compress_kernel(const float* __restrict__ v,
                     const float* __restrict__ wc,
                     const int* __restrict__ idx_in,
                     const int* __restrict__ mel_lengths,
                     float* __restrict__ out) {
    __shared__ float Ws[256 * 68];    // [kk][c] whole W transposed
    __shared__ float Vs[16 * 132];    // [kk][t] per K-step
    __shared__ int   idxs[128];
    const int b   = blockIdx.y;
    const int t0  = blockIdx.x * 128;
    const int tid = threadIdx.x;
    const int melq = mel_lengths[b] >> 2;
    const float* vb = v + (size_t)b * LL * DD;

    if (tid < 128) {
        int t = t0 + tid;
        int ii = idx_in[b * TDS + t];
        idxs[tid] = (t >= melq) ? -1 : ii;
    }
#pragma unroll
    for (int r = 0; r < 16; ++r) {
        int f = tid + r * 256;
        int c = f >> 6;
        int u = f & 63;
        float4 wv = *(const float4*)(wc + (size_t)c * DD + u * 4);
        Ws[(u * 4 + 0) * 68 + c] = wv.x;
        Ws[(u * 4 + 1) * 68 + c] = wv.y;
        Ws[(u * 4 + 2) * 68 + c] = wv.z;
        Ws[(u * 4 + 3) * 68 + c] = wv.w;
    }

    const int tx = tid & 7;      // c-group
    const int ty = tid >> 3;     // t-group (0..31)
    const int tv = tid >> 2;     // 0..63 (+p*64) staging t
    const int uv = tid & 3;      // staging d-chunk
    float acc[8][4];
#pragma unroll
    for (int i = 0; i < 8; ++i)
#pragma unroll
        for (int j = 0; j < 4; ++j) acc[i][j] = 0.f;

    for (int ks = 0; ks < 16; ++ks) {
        const int d0 = ks * 16;
        __syncthreads();
#pragma unroll
        for (int p = 0; p < 2; ++p) {
            int t = tv + p * 64;
            int row = idxs[t];
            float4 vv = make_float4(0.f, 0.f, 0.f, 0.f);
            if (row >= 0) vv = *(const float4*)(vb + (size_t)row * DD + d0 + uv * 4);
            Vs[(uv * 4 + 0) * 132 + t] = vv.x;
            Vs[(uv * 4 + 1) * 132 + t] = vv.y;
            Vs[(uv * 4 + 2) * 132 + t] = vv.z;
            Vs[(uv * 4 + 3) * 132 + t] = vv.w;
        }
        __syncthreads();
#pragma unroll
        for (int kk = 0; kk < 16; ++kk) {
            const float* wrow = Ws + (size_t)(d0 + kk) * 68 + tx * 8;
            float4 a0 = *(const float4*)(wrow);
            float4 a1 = *(const float4*)(wrow + 4);
            float4 bb = *(const float4*)(Vs + kk * 132 + ty * 4);
            const float av[8] = {a0.x, a0.y, a0.z, a0.w, a1.x, a1.y, a1.z, a1.w};
            const float bv[4] = {bb.x, bb.y, bb.z, bb.w};
#pragma unroll
            for (int i = 0; i < 8; ++i)
#pragma unroll
                for (int j = 0; j < 4; ++j)
                    acc[i][j] = fmaf(av[i], bv[j], acc[i][j]);
        }
    }
#pragma unroll
    for (int ci = 0; ci < 8; ++ci) {
        int c = tx * 8 + ci;
        float4 o;
        o.x = acc[ci][0]; o.y = acc[ci][1]; o.z = acc[ci][2]; o.w = acc[ci][3];
        *(float4*)(out + ((size_t)(b * DC + c)) * TDS + t0 + ty * 4) = o;
    }
}

extern "C" void kernel_launch(void* const* d_in, const int* in_sizes, int n_in,
                              void* d_out, int out_size, void* d_ws, size_t ws_size,
                              hipStream_t stream) {
    const float* q    = (const float*)d_in[0];
    const float* k    = (const float*)d_in[1];
    const float* v    = (const float*)d_in[2];
    const float* wc   = (const float*)d_in[3];
    const int*   text = (const int*)d_in[4];
    const int*   mel  = (const int*)d_in[5];

    float* out   = (float*)d_out;
    float* align = out + (size_t)NB * DC * TDS;

    float* wsf = (float*)d_ws;
    float* KP  = wsf;
    float* PEQ = wsf + (size_t)NB * LL * DD;
    int*   IDX = (int*)(PEQ + (size_t)TDS * DD);
    int*   CNT = IDX + (size_t)NB * TDS;
    int*   FLG = CNT + 1;

    hipLaunchKernelGGL(init_cnt_kernel, dim3(1), dim3(64), 0, stream, CNT);
    hipLaunchKernelGGL(peq_kernel, dim3(TDS * DD / 256), dim3(256), 0, stream, PEQ);
    hipLaunchKernelGGL(kp_kernel, dim3(NB * LL * DD / 256), dim3(256), 0, stream,
                       k, text, mel, KP);
    hipLaunchKernelGGL(score_kernel, dim3(TDS / 64, NB), dim3(512), 0, stream,
                       q, KP, PEQ, text, mel, align, IDX, CNT, FLG);
    hipLaunchKernelGGL(refine_kernel, dim3(128), dim3(256), 0, stream,
                       q, k, text, mel, FLG, CNT, IDX);
    hipLaunchKernelGGL(compress_kernel, dim3(TDS / 128, NB), dim3(256), 0, stream,
                       v, wc, IDX, mel, out);
}